// Round 11
// baseline (432.618 us; speedup 1.0000x reference)
//
#include <hip/hip_runtime.h>
#include <hip/hip_cooperative_groups.h>
#include <hip/hip_bf16.h>
#include <cstdint>

namespace cg = cooperative_groups;

static constexpr int BLK   = 256;
static constexpr int CAP   = 48;    // bucket slots/node = 192 B; max degree
                                    // ~35 (Poisson 12.5); overflow -> fixup.
static constexpr int OVMAX = 1024;

typedef __attribute__((ext_vector_type(8))) short bf16x8;
typedef __attribute__((ext_vector_type(4))) float f32x4;

__device__ __forceinline__ float bf16lo(uint32_t u) { return __uint_as_float(u << 16); }
__device__ __forceinline__ float bf16hi(uint32_t u) { return __uint_as_float(u & 0xffff0000u); }
__device__ __forceinline__ unsigned short f2bf(float f) {
    __hip_bfloat16 h = __float2bfloat16(f);
    return *(unsigned short*)&h;
}

struct Params {
    const int* src; const int* dst;
    int* cnt_f; int* cnt_b; int* rank_f; int* rank_b;
    int* adj_f; int* adj_b; int* ovcnt; int* ovlist;
    const float* x; const float* Wf; const float* Wb;
    unsigned short* WTf; unsigned short* WTb;
    unsigned short* h_f; unsigned short* h_b;
    float* dinv_f; float* dinv_b;
    const float* bf; const float* bb;
    float* out;
    int n, ne, gc, gg, gn, gnode, nwords;
};

// One cooperative dispatch; grid-stride virtual blocks per phase; grid.sync()
// replaces the 3 inter-dispatch gaps (~65 us of the round-10 240 us total).
__global__ __launch_bounds__(BLK, 4) void k_all(Params p) {
    cg::grid_group grid = cg::this_grid();
    const int tid  = threadIdx.x;
    const int nblk = gridDim.x;

    // ================= PHASE 1: count+rank  ||  W -> bf16 transposed =======
    // (cnt/ovcnt zeroed by hipMemsetAsync before this launch.)
    // Atomic-return stream is fabric-bound; W^T bulk work hides under it
    // (round-7). Rank stores coalesced (round-8 lesson). Nothing BW-heavy
    // here (round-9 lesson: bulk GEMM traffic serializes vs atomics).
    for (int v = blockIdx.x; v < p.gc + 8; v += nblk) {
        if (v < p.gc) {
            int e = v * BLK + tid;
            if (e < p.ne) {
                int d = p.dst[e], s = p.src[e];
                p.rank_f[e] = atomicAdd(p.cnt_f + d, 1);
                p.rank_b[e] = atomicAdd(p.cnt_b + s, 1);
            }
        } else {
            int wb = v - p.gc;                       // 0..7
            for (int idx = wb * 2048 + tid; idx < (wb + 1) * 2048; idx += BLK) {
                int c = idx >> 7, k = idx & 127;
                p.WTf[c * 128 + k] = f2bf(p.Wf[k * 128 + c]);
                p.WTb[c * 128 + k] = f2bf(p.Wb[k * 128 + c]);
            }
        }
    }
    grid.sync();

    // ================= PHASE 2: fill  ||  MFMA GEMM  ||  dinv ==============
    for (int v = blockIdx.x; v < p.gc + p.gg + p.gn; v += nblk) {
        if (v < p.gc) {
            // bucket fill — atomic-free scatter via precomputed ranks
            int e = v * BLK + tid;
            if (e < p.ne) {
                int s = p.src[e], d = p.dst[e];
                int rf = p.rank_f[e];
                if (rf < CAP) p.adj_f[d * CAP + rf] = s;
                else { int q = atomicAdd(p.ovcnt, 1); if (q < OVMAX) p.ovlist[q] = e * 2 + 0; }
                int rb = p.rank_b[e];
                if (rb < CAP) p.adj_b[s * CAP + rb] = d;
                else { int q = atomicAdd(p.ovcnt, 1); if (q < OVMAX) p.ovlist[q] = e * 2 + 1; }
            }
        } else if (v < p.gc + p.gg) {
            // MFMA GEMM h = bf16(x @ W), unscaled, straight from f32 x
            const int wave = tid >> 6;
            const int lane = tid & 63;
            const int conv = wave >> 1;
            const int n0   = (wave & 1) * 64;
            const int m0   = (v - p.gc) * 16;
            const int q    = lane >> 4;
            const int t16  = lane & 15;

            const unsigned short* __restrict__ WT = conv ? p.WTb : p.WTf;
            unsigned short* __restrict__ h        = conv ? p.h_b : p.h_f;

            int arow = m0 + t16; if (arow >= p.n) arow = p.n - 1;
            const float* __restrict__ xr = p.x + (size_t)arow * 128;
            bf16x8 a[4];
#pragma unroll
            for (int s = 0; s < 4; ++s) {
                float4 p0 = *(const float4*)(xr + s * 32 + q * 8);
                float4 p1 = *(const float4*)(xr + s * 32 + q * 8 + 4);
                bf16x8 av;
                av[0] = (short)f2bf(p0.x); av[1] = (short)f2bf(p0.y);
                av[2] = (short)f2bf(p0.z); av[3] = (short)f2bf(p0.w);
                av[4] = (short)f2bf(p1.x); av[5] = (short)f2bf(p1.y);
                av[6] = (short)f2bf(p1.z); av[7] = (short)f2bf(p1.w);
                a[s] = av;
            }
#pragma unroll
            for (int t = 0; t < 4; ++t) {
                const unsigned short* wrow = WT + (size_t)(n0 + t * 16 + t16) * 128;
                f32x4 c = {0.f, 0.f, 0.f, 0.f};
#pragma unroll
                for (int s = 0; s < 4; ++s) {
                    bf16x8 b = *(const bf16x8*)(wrow + s * 32 + q * 8);
                    c = __builtin_amdgcn_mfma_f32_16x16x32_bf16(a[s], b, c, 0, 0, 0);
                }
#pragma unroll
                for (int r = 0; r < 4; ++r) {
                    int row = m0 + q * 4 + r;
                    if (row < p.n)
                        h[(size_t)row * 128 + n0 + t * 16 + t16] = f2bf(c[r]);
                }
            }
        } else {
            int i = (v - p.gc - p.gg) * BLK + tid;
            if (i < p.n) {
                p.dinv_f[i] = rsqrtf(1.0f + (float)p.cnt_f[i]);
                p.dinv_b[i] = rsqrtf(1.0f + (float)p.cnt_b[i]);
            }
        }
    }
    grid.sync();

    // ================= PHASE 3: gather + fixup =============================
    __shared__ int lst[1024];
    __shared__ int lcnt;
    for (int v = blockIdx.x; v < p.gnode + 8; v += nblk) {
        if (v < p.gnode) {
            const int wave = tid >> 6;
            const int lane = tid & 63;
            const int node = v * 4 + wave;
            if (node < p.n) {
                int cf = p.cnt_f[node], cb = p.cnt_b[node];
                if (cf <= CAP && cb <= CAP) {       // else fixup owns this row
                    float dvsf = p.dinv_f[node], dvsb = p.dinv_b[node];
                    const uint32_t* hf = (const uint32_t*)p.h_f;
                    uint32_t uf = hf[(size_t)node * 64 + lane];
                    uint32_t ub = hf[(size_t)(p.nwords + node * 64 + lane)];
                    float acc0 = dvsf * dvsf * bf16lo(uf) + dvsb * dvsb * bf16lo(ub);
                    float acc1 = dvsf * dvsf * bf16hi(uf) + dvsb * dvsb * bf16hi(ub);

                    const int mt = cf + cb;
                    if (mt <= 64) {
                        int ofs = 0; float sc = 0.f;
                        if (lane < cf) {
                            int nb = p.adj_f[node * CAP + lane];
                            ofs = nb * 64;
                            sc  = dvsf * p.dinv_f[nb];
                        } else if (lane < mt) {
                            int nb = p.adj_b[node * CAP + (lane - cf)];
                            ofs = p.nwords + nb * 64;
                            sc  = dvsb * p.dinv_b[nb];
                        }
                        int j = 0;
                        for (; j + 8 <= mt; j += 8) {
                            int   o0 = __shfl(ofs, j + 0), o1 = __shfl(ofs, j + 1);
                            int   o2 = __shfl(ofs, j + 2), o3 = __shfl(ofs, j + 3);
                            int   o4 = __shfl(ofs, j + 4), o5 = __shfl(ofs, j + 5);
                            int   o6 = __shfl(ofs, j + 6), o7 = __shfl(ofs, j + 7);
                            float s0 = __shfl(sc, j + 0), s1 = __shfl(sc, j + 1);
                            float s2 = __shfl(sc, j + 2), s3 = __shfl(sc, j + 3);
                            float s4 = __shfl(sc, j + 4), s5 = __shfl(sc, j + 5);
                            float s6 = __shfl(sc, j + 6), s7 = __shfl(sc, j + 7);
                            uint32_t u0 = hf[(size_t)(o0 + lane)];
                            uint32_t u1 = hf[(size_t)(o1 + lane)];
                            uint32_t u2 = hf[(size_t)(o2 + lane)];
                            uint32_t u3 = hf[(size_t)(o3 + lane)];
                            uint32_t u4 = hf[(size_t)(o4 + lane)];
                            uint32_t u5 = hf[(size_t)(o5 + lane)];
                            uint32_t u6 = hf[(size_t)(o6 + lane)];
                            uint32_t u7 = hf[(size_t)(o7 + lane)];
                            acc0 = fmaf(s0, bf16lo(u0), acc0); acc1 = fmaf(s0, bf16hi(u0), acc1);
                            acc0 = fmaf(s1, bf16lo(u1), acc0); acc1 = fmaf(s1, bf16hi(u1), acc1);
                            acc0 = fmaf(s2, bf16lo(u2), acc0); acc1 = fmaf(s2, bf16hi(u2), acc1);
                            acc0 = fmaf(s3, bf16lo(u3), acc0); acc1 = fmaf(s3, bf16hi(u3), acc1);
                            acc0 = fmaf(s4, bf16lo(u4), acc0); acc1 = fmaf(s4, bf16hi(u4), acc1);
                            acc0 = fmaf(s5, bf16lo(u5), acc0); acc1 = fmaf(s5, bf16hi(u5), acc1);
                            acc0 = fmaf(s6, bf16lo(u6), acc0); acc1 = fmaf(s6, bf16hi(u6), acc1);
                            acc0 = fmaf(s7, bf16lo(u7), acc0); acc1 = fmaf(s7, bf16hi(u7), acc1);
                        }
                        for (; j + 4 <= mt; j += 4) {
                            int   o0 = __shfl(ofs, j + 0), o1 = __shfl(ofs, j + 1);
                            int   o2 = __shfl(ofs, j + 2), o3 = __shfl(ofs, j + 3);
                            float s0 = __shfl(sc, j + 0), s1 = __shfl(sc, j + 1);
                            float s2 = __shfl(sc, j + 2), s3 = __shfl(sc, j + 3);
                            uint32_t u0 = hf[(size_t)(o0 + lane)];
                            uint32_t u1 = hf[(size_t)(o1 + lane)];
                            uint32_t u2 = hf[(size_t)(o2 + lane)];
                            uint32_t u3 = hf[(size_t)(o3 + lane)];
                            acc0 = fmaf(s0, bf16lo(u0), acc0); acc1 = fmaf(s0, bf16hi(u0), acc1);
                            acc0 = fmaf(s1, bf16lo(u1), acc0); acc1 = fmaf(s1, bf16hi(u1), acc1);
                            acc0 = fmaf(s2, bf16lo(u2), acc0); acc1 = fmaf(s2, bf16hi(u2), acc1);
                            acc0 = fmaf(s3, bf16lo(u3), acc0); acc1 = fmaf(s3, bf16hi(u3), acc1);
                        }
                        for (; j < mt; ++j) {
                            int oj = __shfl(ofs, j); float sj = __shfl(sc, j);
                            uint32_t uj = hf[(size_t)(oj + lane)];
                            acc0 = fmaf(sj, bf16lo(uj), acc0); acc1 = fmaf(sj, bf16hi(uj), acc1);
                        }
                    } else {
                        for (int j = 0; j < cf; ++j) {
                            int nb = p.adj_f[node * CAP + j];
                            float dj = dvsf * p.dinv_f[nb];
                            uint32_t u = hf[(size_t)nb * 64 + lane];
                            acc0 = fmaf(dj, bf16lo(u), acc0); acc1 = fmaf(dj, bf16hi(u), acc1);
                        }
                        for (int j = 0; j < cb; ++j) {
                            int nb = p.adj_b[node * CAP + j];
                            float dj = dvsb * p.dinv_b[nb];
                            uint32_t u = hf[(size_t)(p.nwords + nb * 64 + lane)];
                            acc0 = fmaf(dj, bf16lo(u), acc0); acc1 = fmaf(dj, bf16hi(u), acc1);
                        }
                    }

                    const float2 biasf = ((const float2*)p.bf)[lane];
                    const float2 biasb = ((const float2*)p.bb)[lane];
                    float v0 = acc0 + biasf.x + biasb.x;
                    float v1 = acc1 + biasf.y + biasb.y;
                    ((float2*)p.out)[(size_t)node * 64 + lane] =
                        make_float2(fmaxf(v0, 0.0f), fmaxf(v1, 0.0f));
                }
            }
        } else {
            // ---- fixup: exact recompute of overflowed rows (no-op normally)
            int nov = *p.ovcnt; if (nov > OVMAX) nov = OVMAX;
            if (nov > 0) {
                const uint32_t* hf = (const uint32_t*)p.h_f;
                for (int i = v - p.gnode; i < nov; i += 8) {
                    int code = p.ovlist[i];
                    int e = code >> 1, dir = code & 1;
                    int node = dir ? p.src[e] : p.dst[e];
                    float acc0 = 0.f, acc1 = 0.f;
                    for (int d2 = 0; d2 < 2; ++d2) {
                        const int* key = d2 ? p.src : p.dst;
                        const int* val = d2 ? p.dst : p.src;
                        const float* dinv = d2 ? p.dinv_b : p.dinv_f;
                        int base = d2 ? p.nwords : 0;
                        float dvs = dinv[node];
                        float s0 = 0.f, s1 = 0.f;
                        if (tid < 64) {
                            uint32_t u = hf[(size_t)(base + node * 64 + tid)];
                            s0 = dvs * bf16lo(u); s1 = dvs * bf16hi(u);
                        }
                        for (int start = 0; start < p.ne; start += 1024) {
                            if (tid == 0) lcnt = 0;
                            __syncthreads();
                            int end = min(start + 1024, p.ne);
                            for (int e2 = start + tid; e2 < end; e2 += BLK)
                                if (key[e2] == node) { int q = atomicAdd(&lcnt, 1); lst[q] = val[e2]; }
                            __syncthreads();
                            int mm = lcnt;
                            if (tid < 64) {
                                for (int j = 0; j < mm; ++j) {
                                    int nb = lst[j];
                                    float dv = dinv[nb];
                                    uint32_t u = hf[(size_t)(base + nb * 64 + tid)];
                                    s0 = fmaf(dv, bf16lo(u), s0);
                                    s1 = fmaf(dv, bf16hi(u), s1);
                                }
                            }
                            __syncthreads();
                        }
                        if (tid < 64) { acc0 += dvs * s0; acc1 += dvs * s1; }
                    }
                    if (tid < 64) {
                        float2 biasf = ((const float2*)p.bf)[tid];
                        float2 biasb = ((const float2*)p.bb)[tid];
                        float v0 = acc0 + biasf.x + biasb.x;
                        float v1 = acc1 + biasf.y + biasb.y;
                        ((float2*)p.out)[(size_t)node * 64 + tid] =
                            make_float2(fmaxf(v0, 0.0f), fmaxf(v1, 0.0f));
                    }
                    __syncthreads();
                }
            }
        }
    }
}

// ============================================================ launcher =====
extern "C" void kernel_launch(void* const* d_in, const int* in_sizes, int n_in,
                              void* d_out, int out_size, void* d_ws, size_t ws_size,
                              hipStream_t stream) {
    const float* x  = (const float*)d_in[0];
    const int*   ei = (const int*)d_in[1];
    const float* Wf = (const float*)d_in[2];
    const float* bf = (const float*)d_in[3];
    const float* Wb = (const float*)d_in[4];
    const float* bb = (const float*)d_in[5];

    const int n  = in_sizes[0] / 128;   // 50000
    const int ne = in_sizes[1] / 2;     // 625000
    const int* src = ei;
    const int* dst = ei + ne;
    float* out = (float*)d_out;

    // workspace layout (16B-aligned; n, ne multiples of 4)
    // h_f and h_b contiguous (gather addresses h_b as h_f + nwords dwords)
    char* w = (char*)d_ws;
    unsigned short* h_f = (unsigned short*)w;   w += (size_t)n * 128 * 2;
    unsigned short* h_b = (unsigned short*)w;   w += (size_t)n * 128 * 2;
    int* adj_f = (int*)w;                       w += (size_t)n * CAP * 4;
    int* adj_b = (int*)w;                       w += (size_t)n * CAP * 4;
    int* rank_f = (int*)w;                      w += (size_t)ne * 4;
    int* rank_b = (int*)w;                      w += (size_t)ne * 4;
    float* dinv_f = (float*)w;                  w += (size_t)n * 4;
    float* dinv_b = (float*)w;                  w += (size_t)n * 4;
    unsigned short* WTf = (unsigned short*)w;   w += 128 * 128 * 2;
    unsigned short* WTb = (unsigned short*)w;   w += 128 * 128 * 2;
    int* cnt_f = (int*)w;                       w += (size_t)n * 4;   // ---- zero
    int* cnt_b = (int*)w;                       w += (size_t)n * 4;   //  region
    int* ovcnt = (int*)w;                       w += 8 * 4;           // ----
    int* ovlist = (int*)w;                      w += OVMAX * 4;

    Params p;
    p.src = src; p.dst = dst;
    p.cnt_f = cnt_f; p.cnt_b = cnt_b; p.rank_f = rank_f; p.rank_b = rank_b;
    p.adj_f = adj_f; p.adj_b = adj_b; p.ovcnt = ovcnt; p.ovlist = ovlist;
    p.x = x; p.Wf = Wf; p.Wb = Wb; p.WTf = WTf; p.WTb = WTb;
    p.h_f = h_f; p.h_b = h_b; p.dinv_f = dinv_f; p.dinv_b = dinv_b;
    p.bf = bf; p.bb = bb; p.out = out;
    p.n = n; p.ne = ne;
    p.gc = (ne + BLK - 1) / BLK;        // 2442
    p.gg = (n + 15) / 16;               // 3125
    p.gn = (n + BLK - 1) / BLK;         // 196
    p.gnode = (n + 3) / 4;              // 12500
    p.nwords = n * 64;

    // zero cnt_f | cnt_b | ovcnt before the atomics (strict ordering)
    hipMemsetAsync(cnt_f, 0, (size_t)(2 * n + 8) * 4, stream);

    // co-resident grid for grid.sync(): occupancy * 256 CUs (gfx950)
    int nbpc = 0;
    hipOccupancyMaxActiveBlocksPerMultiprocessor(&nbpc, k_all, BLK, 0);
    if (nbpc < 1) nbpc = 1;
    int grid = nbpc * 256;
    if (grid > 12508) grid = 12508;      // no more blocks than peak work

    void* args[] = { (void*)&p };
    hipLaunchCooperativeKernel(k_all, dim3(grid), dim3(BLK), args, 0, stream);
}

// Round 12
// 239.963 us; speedup vs baseline: 1.8029x; 1.8029x over previous
//
#include <hip/hip_runtime.h>
#include <hip/hip_bf16.h>
#include <cstdint>

static constexpr int BLK   = 256;
static constexpr int CAP   = 48;    // bucket slots/node = 192 B; max degree
                                    // ~35 (Poisson 12.5); overflow -> fixup.
static constexpr int OVMAX = 1024;

typedef __attribute__((ext_vector_type(8))) short bf16x8;
typedef __attribute__((ext_vector_type(4))) float f32x4;

__device__ __forceinline__ float bf16lo(uint32_t u) { return __uint_as_float(u << 16); }
__device__ __forceinline__ float bf16hi(uint32_t u) { return __uint_as_float(u & 0xffff0000u); }
__device__ __forceinline__ unsigned short f2bf(float f) {
    __hip_bfloat16 h = __float2bfloat16(f);
    return *(unsigned short*)&h;
}

// ============================================================ COUNT ========
// blocks [0, gc2):  count + rank, 2 edges/thread (4 atomic-returns in
//   flight/lane; grid still ~4.8 blocks/CU — rounds 4/5 showed the wall is
//   outstanding-atomics * resident-waves; 2-edge is the sweet spot).
//   Rank stores coalesced (round-8 lesson). No bulk-BW work here except the
//   tiny W^T (round-9 lesson: GEMM traffic serializes vs the atomic fabric).
// blocks [gc2, +8): W -> bf16 transposed (128 KB; hides under atomic wall).
__global__ __launch_bounds__(BLK) void k_count(
        const int* __restrict__ src, const int* __restrict__ dst,
        int* __restrict__ cnt_f, int* __restrict__ cnt_b,
        int* __restrict__ rank_f, int* __restrict__ rank_b, int ne,
        const float* __restrict__ Wf, const float* __restrict__ Wb,
        unsigned short* __restrict__ WTf, unsigned short* __restrict__ WTb,
        int gc2) {
    const int bid = blockIdx.x;
    if (bid < gc2) {
        int e0 = bid * (BLK * 2) + threadIdx.x;
        int e1 = e0 + BLK;
        if (e1 < ne) {
            int d0 = dst[e0], s0 = src[e0];
            int d1 = dst[e1], s1 = src[e1];
            int rf0 = atomicAdd(cnt_f + d0, 1);
            int rf1 = atomicAdd(cnt_f + d1, 1);
            int rb0 = atomicAdd(cnt_b + s0, 1);
            int rb1 = atomicAdd(cnt_b + s1, 1);
            rank_f[e0] = rf0; rank_f[e1] = rf1;
            rank_b[e0] = rb0; rank_b[e1] = rb1;
        } else if (e0 < ne) {
            int d0 = dst[e0], s0 = src[e0];
            rank_f[e0] = atomicAdd(cnt_f + d0, 1);
            rank_b[e0] = atomicAdd(cnt_b + s0, 1);
        }
        return;
    }
    int wb = bid - gc2;                          // 0..7
    for (int idx = wb * 2048 + threadIdx.x; idx < (wb + 1) * 2048; idx += BLK) {
        int c = idx >> 7, k = idx & 127;
        WTf[c * 128 + k] = f2bf(Wf[k * 128 + c]);
        WTb[c * 128 + k] = f2bf(Wb[k * 128 + c]);
    }
}

// ============================================================ PHASE B ======
// blocks [0, gc):          bucket fill — atomic-free scattered stores via
//                          precomputed ranks (scatter-LATENCY bound, VALUs
//                          idle -> legit overlap partner for the GEMM).
// blocks [gc, gc+gg):      MFMA GEMM h = bf16(x @ W) unscaled, from f32 x.
// blocks [gc+gg, +gn):     dinv = rsqrt(1 + cnt), both directions.
__global__ __launch_bounds__(BLK) void k_phaseB(
        const int* __restrict__ src, const int* __restrict__ dst,
        const int* __restrict__ rank_f, const int* __restrict__ rank_b,
        int* __restrict__ adj_f, int* __restrict__ adj_b,
        int* __restrict__ ovcnt, int* __restrict__ ovlist, int ne,
        const float* __restrict__ x,
        const unsigned short* __restrict__ WTf,
        const unsigned short* __restrict__ WTb,
        unsigned short* __restrict__ h_f, unsigned short* __restrict__ h_b,
        const int* __restrict__ cnt_f, const int* __restrict__ cnt_b,
        float* __restrict__ dinv_f, float* __restrict__ dinv_b,
        int n, int gc, int gg) {
    const int bid = blockIdx.x;
    if (bid < gc) {
        int e = bid * BLK + threadIdx.x;
        if (e < ne) {
            int s = src[e], d = dst[e];
            int rf = rank_f[e];
            if (rf < CAP) adj_f[d * CAP + rf] = s;
            else { int q = atomicAdd(ovcnt, 1); if (q < OVMAX) ovlist[q] = e * 2 + 0; }
            int rb = rank_b[e];
            if (rb < CAP) adj_b[s * CAP + rb] = d;
            else { int q = atomicAdd(ovcnt, 1); if (q < OVMAX) ovlist[q] = e * 2 + 1; }
        }
        return;
    }
    if (bid < gc + gg) {
        // ---- MFMA GEMM (unscaled) ----
        const int wave = threadIdx.x >> 6;
        const int lane = threadIdx.x & 63;
        const int conv = wave >> 1;
        const int n0   = (wave & 1) * 64;
        const int m0   = (bid - gc) * 16;
        const int q    = lane >> 4;
        const int t16  = lane & 15;

        const unsigned short* __restrict__ WT = conv ? WTb : WTf;
        unsigned short* __restrict__ h        = conv ? h_b : h_f;

        int arow = m0 + t16; if (arow >= n) arow = n - 1;
        const float* __restrict__ xr = x + (size_t)arow * 128;
        bf16x8 a[4];
#pragma unroll
        for (int s = 0; s < 4; ++s) {
            float4 p0 = *(const float4*)(xr + s * 32 + q * 8);
            float4 p1 = *(const float4*)(xr + s * 32 + q * 8 + 4);
            bf16x8 v;
            v[0] = (short)f2bf(p0.x); v[1] = (short)f2bf(p0.y);
            v[2] = (short)f2bf(p0.z); v[3] = (short)f2bf(p0.w);
            v[4] = (short)f2bf(p1.x); v[5] = (short)f2bf(p1.y);
            v[6] = (short)f2bf(p1.z); v[7] = (short)f2bf(p1.w);
            a[s] = v;
        }
#pragma unroll
        for (int t = 0; t < 4; ++t) {
            const unsigned short* wrow = WT + (size_t)(n0 + t * 16 + t16) * 128;
            f32x4 c = {0.f, 0.f, 0.f, 0.f};
#pragma unroll
            for (int s = 0; s < 4; ++s) {
                bf16x8 b = *(const bf16x8*)(wrow + s * 32 + q * 8);
                c = __builtin_amdgcn_mfma_f32_16x16x32_bf16(a[s], b, c, 0, 0, 0);
            }
#pragma unroll
            for (int r = 0; r < 4; ++r) {
                int row = m0 + q * 4 + r;
                if (row < n)
                    h[(size_t)row * 128 + n0 + t * 16 + t16] = f2bf(c[r]);
            }
        }
        return;
    }
    int i = (bid - gc - gg) * BLK + threadIdx.x;
    if (i < n) {
        dinv_f[i] = rsqrtf(1.0f + (float)cnt_f[i]);
        dinv_b[i] = rsqrtf(1.0f + (float)cnt_b[i]);
    }
}

// ============================================================ GATHER =======
// blocks [0, gnode):       wave per node; lane owns one bf16x2 dword.
//   Unified direction loop (round-10 win): both convs' neighbors in one
//   lane-list; h_b addressed as h_f + nwords; one 8-wide MLP loop.
// blocks [gnode, gnode+8): exact recompute of CAP-overflowed rows (no-op
//   when *ovcnt == 0, the expected case).
__global__ __launch_bounds__(BLK) void k_gatherX(
        const int* __restrict__ cnt_f, const int* __restrict__ adj_f,
        const int* __restrict__ cnt_b, const int* __restrict__ adj_b,
        const float* __restrict__ dinv_f, const float* __restrict__ dinv_b,
        const uint32_t* __restrict__ hf, const uint32_t* __restrict__ hb,
        const float* __restrict__ bf, const float* __restrict__ bb,
        float* __restrict__ out, int n, int gnode, int nwords,
        const int* __restrict__ ovcnt, const int* __restrict__ ovlist,
        const int* __restrict__ src, const int* __restrict__ dst, int ne) {
    const int bid = blockIdx.x;
    if (bid < gnode) {
        const int wave = threadIdx.x >> 6;
        const int lane = threadIdx.x & 63;
        const int node = bid * 4 + wave;
        if (node >= n) return;

        int cf = cnt_f[node], cb = cnt_b[node];
        if (cf > CAP || cb > CAP) return;          // fixup owns this row

        float dvsf = dinv_f[node], dvsb = dinv_b[node];
        uint32_t uf = hf[(size_t)node * 64 + lane];
        uint32_t ub = hf[(size_t)(nwords + node * 64 + lane)];
        float acc0 = dvsf * dvsf * bf16lo(uf) + dvsb * dvsb * bf16lo(ub);
        float acc1 = dvsf * dvsf * bf16hi(uf) + dvsb * dvsb * bf16hi(ub);

        const int mt = cf + cb;
        if (mt <= 64) {
            int ofs = 0; float sc = 0.f;
            if (lane < cf) {
                int nb = adj_f[node * CAP + lane];
                ofs = nb * 64;
                sc  = dvsf * dinv_f[nb];
            } else if (lane < mt) {
                int nb = adj_b[node * CAP + (lane - cf)];
                ofs = nwords + nb * 64;
                sc  = dvsb * dinv_b[nb];
            }
            int j = 0;
            for (; j + 8 <= mt; j += 8) {
                int   o0 = __shfl(ofs, j + 0), o1 = __shfl(ofs, j + 1);
                int   o2 = __shfl(ofs, j + 2), o3 = __shfl(ofs, j + 3);
                int   o4 = __shfl(ofs, j + 4), o5 = __shfl(ofs, j + 5);
                int   o6 = __shfl(ofs, j + 6), o7 = __shfl(ofs, j + 7);
                float s0 = __shfl(sc, j + 0), s1 = __shfl(sc, j + 1);
                float s2 = __shfl(sc, j + 2), s3 = __shfl(sc, j + 3);
                float s4 = __shfl(sc, j + 4), s5 = __shfl(sc, j + 5);
                float s6 = __shfl(sc, j + 6), s7 = __shfl(sc, j + 7);
                uint32_t u0 = hf[(size_t)(o0 + lane)];
                uint32_t u1 = hf[(size_t)(o1 + lane)];
                uint32_t u2 = hf[(size_t)(o2 + lane)];
                uint32_t u3 = hf[(size_t)(o3 + lane)];
                uint32_t u4 = hf[(size_t)(o4 + lane)];
                uint32_t u5 = hf[(size_t)(o5 + lane)];
                uint32_t u6 = hf[(size_t)(o6 + lane)];
                uint32_t u7 = hf[(size_t)(o7 + lane)];
                acc0 = fmaf(s0, bf16lo(u0), acc0); acc1 = fmaf(s0, bf16hi(u0), acc1);
                acc0 = fmaf(s1, bf16lo(u1), acc0); acc1 = fmaf(s1, bf16hi(u1), acc1);
                acc0 = fmaf(s2, bf16lo(u2), acc0); acc1 = fmaf(s2, bf16hi(u2), acc1);
                acc0 = fmaf(s3, bf16lo(u3), acc0); acc1 = fmaf(s3, bf16hi(u3), acc1);
                acc0 = fmaf(s4, bf16lo(u4), acc0); acc1 = fmaf(s4, bf16hi(u4), acc1);
                acc0 = fmaf(s5, bf16lo(u5), acc0); acc1 = fmaf(s5, bf16hi(u5), acc1);
                acc0 = fmaf(s6, bf16lo(u6), acc0); acc1 = fmaf(s6, bf16hi(u6), acc1);
                acc0 = fmaf(s7, bf16lo(u7), acc0); acc1 = fmaf(s7, bf16hi(u7), acc1);
            }
            for (; j + 4 <= mt; j += 4) {
                int   o0 = __shfl(ofs, j + 0), o1 = __shfl(ofs, j + 1);
                int   o2 = __shfl(ofs, j + 2), o3 = __shfl(ofs, j + 3);
                float s0 = __shfl(sc, j + 0), s1 = __shfl(sc, j + 1);
                float s2 = __shfl(sc, j + 2), s3 = __shfl(sc, j + 3);
                uint32_t u0 = hf[(size_t)(o0 + lane)];
                uint32_t u1 = hf[(size_t)(o1 + lane)];
                uint32_t u2 = hf[(size_t)(o2 + lane)];
                uint32_t u3 = hf[(size_t)(o3 + lane)];
                acc0 = fmaf(s0, bf16lo(u0), acc0); acc1 = fmaf(s0, bf16hi(u0), acc1);
                acc0 = fmaf(s1, bf16lo(u1), acc0); acc1 = fmaf(s1, bf16hi(u1), acc1);
                acc0 = fmaf(s2, bf16lo(u2), acc0); acc1 = fmaf(s2, bf16hi(u2), acc1);
                acc0 = fmaf(s3, bf16lo(u3), acc0); acc1 = fmaf(s3, bf16hi(u3), acc1);
            }
            for (; j < mt; ++j) {
                int oj = __shfl(ofs, j); float sj = __shfl(sc, j);
                uint32_t uj = hf[(size_t)(oj + lane)];
                acc0 = fmaf(sj, bf16lo(uj), acc0); acc1 = fmaf(sj, bf16hi(uj), acc1);
            }
        } else {
            // ultra-rare exact fallback (cf+cb > 64)
            for (int j = 0; j < cf; ++j) {
                int nb = adj_f[node * CAP + j];
                float dj = dvsf * dinv_f[nb];
                uint32_t u = hf[(size_t)nb * 64 + lane];
                acc0 = fmaf(dj, bf16lo(u), acc0); acc1 = fmaf(dj, bf16hi(u), acc1);
            }
            for (int j = 0; j < cb; ++j) {
                int nb = adj_b[node * CAP + j];
                float dj = dvsb * dinv_b[nb];
                uint32_t u = hf[(size_t)(nwords + nb * 64 + lane)];
                acc0 = fmaf(dj, bf16lo(u), acc0); acc1 = fmaf(dj, bf16hi(u), acc1);
            }
        }

        const float2 biasf = ((const float2*)bf)[lane];
        const float2 biasb = ((const float2*)bb)[lane];
        float v0 = acc0 + biasf.x + biasb.x;
        float v1 = acc1 + biasf.y + biasb.y;
        ((float2*)out)[(size_t)node * 64 + lane] =
            make_float2(fmaxf(v0, 0.0f), fmaxf(v1, 0.0f));
        return;
    }

    // ---- fixup blocks: exact recompute of overflowed rows ----
    int nov = *ovcnt; if (nov > OVMAX) nov = OVMAX;
    if (nov == 0) return;
    __shared__ int lst[4096];
    __shared__ int lcnt;
    const int tid = threadIdx.x;
    for (int i = bid - gnode; i < nov; i += 8) {
        int code = ovlist[i];
        int e = code >> 1, dir = code & 1;
        int node = dir ? src[e] : dst[e];
        float acc0 = 0.f, acc1 = 0.f;
        for (int d2 = 0; d2 < 2; ++d2) {
            const int* key = d2 ? src : dst;
            const int* val = d2 ? dst : src;
            const float* dinv = d2 ? dinv_b : dinv_f;
            int base = d2 ? nwords : 0;
            float dvs = dinv[node];
            float s0 = 0.f, s1 = 0.f;
            if (tid < 64) {
                uint32_t u = hf[(size_t)(base + node * 64 + tid)];
                s0 = dvs * bf16lo(u); s1 = dvs * bf16hi(u);
            }
            for (int start = 0; start < ne; start += 4096) {
                if (tid == 0) lcnt = 0;
                __syncthreads();
                int end = min(start + 4096, ne);
                for (int e2 = start + tid; e2 < end; e2 += BLK)
                    if (key[e2] == node) { int q = atomicAdd(&lcnt, 1); lst[q] = val[e2]; }
                __syncthreads();
                int mm = lcnt;
                if (tid < 64) {
                    for (int j = 0; j < mm; ++j) {
                        int nb = lst[j];
                        float dv = dinv[nb];
                        uint32_t u = hf[(size_t)(base + nb * 64 + tid)];
                        s0 = fmaf(dv, bf16lo(u), s0);
                        s1 = fmaf(dv, bf16hi(u), s1);
                    }
                }
                __syncthreads();
            }
            if (tid < 64) { acc0 += dvs * s0; acc1 += dvs * s1; }
        }
        if (tid < 64) {
            float2 biasf = ((const float2*)bf)[tid];
            float2 biasb = ((const float2*)bb)[tid];
            float v0 = acc0 + biasf.x + biasb.x;
            float v1 = acc1 + biasf.y + biasb.y;
            ((float2*)out)[(size_t)node * 64 + tid] =
                make_float2(fmaxf(v0, 0.0f), fmaxf(v1, 0.0f));
        }
        __syncthreads();
    }
}

// ============================================================ launcher =====
extern "C" void kernel_launch(void* const* d_in, const int* in_sizes, int n_in,
                              void* d_out, int out_size, void* d_ws, size_t ws_size,
                              hipStream_t stream) {
    const float* x  = (const float*)d_in[0];
    const int*   ei = (const int*)d_in[1];
    const float* Wf = (const float*)d_in[2];
    const float* bf = (const float*)d_in[3];
    const float* Wb = (const float*)d_in[4];
    const float* bb = (const float*)d_in[5];

    const int n  = in_sizes[0] / 128;   // 50000
    const int ne = in_sizes[1] / 2;     // 625000
    const int* src = ei;
    const int* dst = ei + ne;
    float* out = (float*)d_out;

    // workspace layout (16B-aligned; n, ne multiples of 4)
    // h_f and h_b contiguous (gather addresses h_b as h_f + nwords dwords)
    char* w = (char*)d_ws;
    unsigned short* h_f = (unsigned short*)w;   w += (size_t)n * 128 * 2;
    unsigned short* h_b = (unsigned short*)w;   w += (size_t)n * 128 * 2;
    int* adj_f = (int*)w;                       w += (size_t)n * CAP * 4;
    int* adj_b = (int*)w;                       w += (size_t)n * CAP * 4;
    int* rank_f = (int*)w;                      w += (size_t)ne * 4;
    int* rank_b = (int*)w;                      w += (size_t)ne * 4;
    float* dinv_f = (float*)w;                  w += (size_t)n * 4;
    float* dinv_b = (float*)w;                  w += (size_t)n * 4;
    unsigned short* WTf = (unsigned short*)w;   w += 128 * 128 * 2;
    unsigned short* WTb = (unsigned short*)w;   w += 128 * 128 * 2;
    int* cnt_f = (int*)w;                       w += (size_t)n * 4;   // ---- zero
    int* cnt_b = (int*)w;                       w += (size_t)n * 4;   //  region
    int* ovcnt = (int*)w;                       w += 8 * 4;           // ----
    int* ovlist = (int*)w;                      w += OVMAX * 4;

    const int gc2   = (ne + BLK * 2 - 1) / (BLK * 2);   // 1221 count blocks
    const int gc    = (ne + BLK - 1) / BLK;             // 2442 fill blocks
    const int gg    = (n + 15) / 16;                    // 3125 gemm blocks
    const int gn    = (n + BLK - 1) / BLK;              // 196
    const int gnode = (n + 3) / 4;                      // 12500

    hipMemsetAsync(cnt_f, 0, (size_t)(2 * n + 8) * 4, stream);

    k_count <<<gc2 + 8, BLK, 0, stream>>>(src, dst, cnt_f, cnt_b,
                                          rank_f, rank_b, ne,
                                          Wf, Wb, WTf, WTb, gc2);

    k_phaseB<<<gc + gg + gn, BLK, 0, stream>>>(src, dst, rank_f, rank_b,
                                               adj_f, adj_b, ovcnt, ovlist, ne,
                                               x, WTf, WTb, h_f, h_b,
                                               cnt_f, cnt_b, dinv_f, dinv_b,
                                               n, gc, gg);

    k_gatherX<<<gnode + 8, BLK, 0, stream>>>(cnt_f, adj_f, cnt_b, adj_b,
                                             dinv_f, dinv_b,
                                             (const uint32_t*)h_f,
                                             (const uint32_t*)h_b,
                                             bf, bb, out, n, gnode, n * 64,
                                             ovcnt, ovlist, src, dst, ne);
}

// Round 13
// 235.165 us; speedup vs baseline: 1.8396x; 1.0204x over previous
//
#include <hip/hip_runtime.h>
#include <hip/hip_bf16.h>
#include <cstdint>

static constexpr int BLK   = 256;
static constexpr int CAP   = 40;    // bucket slots/node; ushort slots -> 80 B
                                    // bucket. Max degree ~35 (Poisson 12.5);
                                    // P(deg>40) ~ 3e-10; overflow -> fixup.
static constexpr int OVMAX = 1024;

typedef __attribute__((ext_vector_type(8))) short bf16x8;
typedef __attribute__((ext_vector_type(4))) float f32x4;

__device__ __forceinline__ float bf16lo(uint32_t u) { return __uint_as_float(u << 16); }
__device__ __forceinline__ float bf16hi(uint32_t u) { return __uint_as_float(u & 0xffff0000u); }
__device__ __forceinline__ unsigned short f2bf(float f) {
    __hip_bfloat16 h = __float2bfloat16(f);
    return *(unsigned short*)&h;
}

// ============================================================ COUNT ========
// blocks [0, gc2):  count + rank, 2 edges/thread (4 atomic-returns in
//   flight/lane). Rank stored as u8 (degree << 255), coalesced (r8 lesson:
//   never scatter on the atomic return; r9 lesson: no bulk BW work beside
//   the atomic fabric stream).
// blocks [gc2, +8): W -> bf16 transposed (tiny; hides under atomic wall).
__global__ __launch_bounds__(BLK) void k_count(
        const int* __restrict__ src, const int* __restrict__ dst,
        int* __restrict__ cnt_f, int* __restrict__ cnt_b,
        unsigned char* __restrict__ rank_f, unsigned char* __restrict__ rank_b,
        int ne,
        const float* __restrict__ Wf, const float* __restrict__ Wb,
        unsigned short* __restrict__ WTf, unsigned short* __restrict__ WTb,
        int gc2) {
    const int bid = blockIdx.x;
    if (bid < gc2) {
        int e0 = bid * (BLK * 2) + threadIdx.x;
        int e1 = e0 + BLK;
        if (e1 < ne) {
            int d0 = dst[e0], s0 = src[e0];
            int d1 = dst[e1], s1 = src[e1];
            int rf0 = atomicAdd(cnt_f + d0, 1);
            int rf1 = atomicAdd(cnt_f + d1, 1);
            int rb0 = atomicAdd(cnt_b + s0, 1);
            int rb1 = atomicAdd(cnt_b + s1, 1);
            rank_f[e0] = (unsigned char)min(rf0, 255);
            rank_f[e1] = (unsigned char)min(rf1, 255);
            rank_b[e0] = (unsigned char)min(rb0, 255);
            rank_b[e1] = (unsigned char)min(rb1, 255);
        } else if (e0 < ne) {
            int d0 = dst[e0], s0 = src[e0];
            rank_f[e0] = (unsigned char)min(atomicAdd(cnt_f + d0, 1), 255);
            rank_b[e0] = (unsigned char)min(atomicAdd(cnt_b + s0, 1), 255);
        }
        return;
    }
    int wb = bid - gc2;                          // 0..7
    for (int idx = wb * 2048 + threadIdx.x; idx < (wb + 1) * 2048; idx += BLK) {
        int c = idx >> 7, k = idx & 127;
        WTf[c * 128 + k] = f2bf(Wf[k * 128 + c]);
        WTb[c * 128 + k] = f2bf(Wb[k * 128 + c]);
    }
}

// ============================================================ PHASE B ======
// blocks [0, gc):          bucket fill — atomic-free 2 B scattered stores
//                          (ushort adj, 8 MB region: ~half the line churn
//                          of the int version; r12 counter evidence).
// blocks [gc, gc+gg):      MFMA GEMM h = bf16(x @ W) unscaled, from f32 x.
// blocks [gc+gg, +gn):     dinv = rsqrt(1 + cnt), both directions.
__global__ __launch_bounds__(BLK) void k_phaseB(
        const int* __restrict__ src, const int* __restrict__ dst,
        const unsigned char* __restrict__ rank_f,
        const unsigned char* __restrict__ rank_b,
        unsigned short* __restrict__ adj_f, unsigned short* __restrict__ adj_b,
        int* __restrict__ ovcnt, int* __restrict__ ovlist, int ne,
        const float* __restrict__ x,
        const unsigned short* __restrict__ WTf,
        const unsigned short* __restrict__ WTb,
        unsigned short* __restrict__ h_f, unsigned short* __restrict__ h_b,
        const int* __restrict__ cnt_f, const int* __restrict__ cnt_b,
        float* __restrict__ dinv_f, float* __restrict__ dinv_b,
        int n, int gc, int gg) {
    const int bid = blockIdx.x;
    if (bid < gc) {
        int e = bid * BLK + threadIdx.x;
        if (e < ne) {
            int s = src[e], d = dst[e];
            int rf = rank_f[e];
            if (rf < CAP) adj_f[d * CAP + rf] = (unsigned short)s;
            else { int q = atomicAdd(ovcnt, 1); if (q < OVMAX) ovlist[q] = e * 2 + 0; }
            int rb = rank_b[e];
            if (rb < CAP) adj_b[s * CAP + rb] = (unsigned short)d;
            else { int q = atomicAdd(ovcnt, 1); if (q < OVMAX) ovlist[q] = e * 2 + 1; }
        }
        return;
    }
    if (bid < gc + gg) {
        // ---- MFMA GEMM (unscaled) ----
        const int wave = threadIdx.x >> 6;
        const int lane = threadIdx.x & 63;
        const int conv = wave >> 1;
        const int n0   = (wave & 1) * 64;
        const int m0   = (bid - gc) * 16;
        const int q    = lane >> 4;
        const int t16  = lane & 15;

        const unsigned short* __restrict__ WT = conv ? WTb : WTf;
        unsigned short* __restrict__ h        = conv ? h_b : h_f;

        int arow = m0 + t16; if (arow >= n) arow = n - 1;
        const float* __restrict__ xr = x + (size_t)arow * 128;
        bf16x8 a[4];
#pragma unroll
        for (int s = 0; s < 4; ++s) {
            float4 p0 = *(const float4*)(xr + s * 32 + q * 8);
            float4 p1 = *(const float4*)(xr + s * 32 + q * 8 + 4);
            bf16x8 v;
            v[0] = (short)f2bf(p0.x); v[1] = (short)f2bf(p0.y);
            v[2] = (short)f2bf(p0.z); v[3] = (short)f2bf(p0.w);
            v[4] = (short)f2bf(p1.x); v[5] = (short)f2bf(p1.y);
            v[6] = (short)f2bf(p1.z); v[7] = (short)f2bf(p1.w);
            a[s] = v;
        }
#pragma unroll
        for (int t = 0; t < 4; ++t) {
            const unsigned short* wrow = WT + (size_t)(n0 + t * 16 + t16) * 128;
            f32x4 c = {0.f, 0.f, 0.f, 0.f};
#pragma unroll
            for (int s = 0; s < 4; ++s) {
                bf16x8 b = *(const bf16x8*)(wrow + s * 32 + q * 8);
                c = __builtin_amdgcn_mfma_f32_16x16x32_bf16(a[s], b, c, 0, 0, 0);
            }
#pragma unroll
            for (int r = 0; r < 4; ++r) {
                int row = m0 + q * 4 + r;
                if (row < n)
                    h[(size_t)row * 128 + n0 + t * 16 + t16] = f2bf(c[r]);
            }
        }
        return;
    }
    int i = (bid - gc - gg) * BLK + threadIdx.x;
    if (i < n) {
        dinv_f[i] = rsqrtf(1.0f + (float)cnt_f[i]);
        dinv_b[i] = rsqrtf(1.0f + (float)cnt_b[i]);
    }
}

// ============================================================ GATHER =======
// blocks [0, gnode):       wave per node; lane owns one bf16x2 dword.
//   Unified direction loop (round-10 win): both convs' neighbors in one
//   lane-list; h_b addressed as h_f + nwords; one 8-wide MLP loop.
// blocks [gnode, gnode+8): exact recompute of CAP-overflowed rows (no-op
//   when *ovcnt == 0, the expected case).
__global__ __launch_bounds__(BLK) void k_gatherX(
        const int* __restrict__ cnt_f, const unsigned short* __restrict__ adj_f,
        const int* __restrict__ cnt_b, const unsigned short* __restrict__ adj_b,
        const float* __restrict__ dinv_f, const float* __restrict__ dinv_b,
        const uint32_t* __restrict__ hf, const uint32_t* __restrict__ hb,
        const float* __restrict__ bf, const float* __restrict__ bb,
        float* __restrict__ out, int n, int gnode, int nwords,
        const int* __restrict__ ovcnt, const int* __restrict__ ovlist,
        const int* __restrict__ src, const int* __restrict__ dst, int ne) {
    const int bid = blockIdx.x;
    if (bid < gnode) {
        const int wave = threadIdx.x >> 6;
        const int lane = threadIdx.x & 63;
        const int node = bid * 4 + wave;
        if (node >= n) return;

        int cf = cnt_f[node], cb = cnt_b[node];
        if (cf > CAP || cb > CAP) return;          // fixup owns this row

        float dvsf = dinv_f[node], dvsb = dinv_b[node];
        uint32_t uf = hf[(size_t)node * 64 + lane];
        uint32_t ub = hf[(size_t)(nwords + node * 64 + lane)];
        float acc0 = dvsf * dvsf * bf16lo(uf) + dvsb * dvsb * bf16lo(ub);
        float acc1 = dvsf * dvsf * bf16hi(uf) + dvsb * dvsb * bf16hi(ub);

        const int mt = cf + cb;
        if (mt <= 64) {
            int ofs = 0; float sc = 0.f;
            if (lane < cf) {
                int nb = adj_f[node * CAP + lane];
                ofs = nb * 64;
                sc  = dvsf * dinv_f[nb];
            } else if (lane < mt) {
                int nb = adj_b[node * CAP + (lane - cf)];
                ofs = nwords + nb * 64;
                sc  = dvsb * dinv_b[nb];
            }
            int j = 0;
            for (; j + 8 <= mt; j += 8) {
                int   o0 = __shfl(ofs, j + 0), o1 = __shfl(ofs, j + 1);
                int   o2 = __shfl(ofs, j + 2), o3 = __shfl(ofs, j + 3);
                int   o4 = __shfl(ofs, j + 4), o5 = __shfl(ofs, j + 5);
                int   o6 = __shfl(ofs, j + 6), o7 = __shfl(ofs, j + 7);
                float s0 = __shfl(sc, j + 0), s1 = __shfl(sc, j + 1);
                float s2 = __shfl(sc, j + 2), s3 = __shfl(sc, j + 3);
                float s4 = __shfl(sc, j + 4), s5 = __shfl(sc, j + 5);
                float s6 = __shfl(sc, j + 6), s7 = __shfl(sc, j + 7);
                uint32_t u0 = hf[(size_t)(o0 + lane)];
                uint32_t u1 = hf[(size_t)(o1 + lane)];
                uint32_t u2 = hf[(size_t)(o2 + lane)];
                uint32_t u3 = hf[(size_t)(o3 + lane)];
                uint32_t u4 = hf[(size_t)(o4 + lane)];
                uint32_t u5 = hf[(size_t)(o5 + lane)];
                uint32_t u6 = hf[(size_t)(o6 + lane)];
                uint32_t u7 = hf[(size_t)(o7 + lane)];
                acc0 = fmaf(s0, bf16lo(u0), acc0); acc1 = fmaf(s0, bf16hi(u0), acc1);
                acc0 = fmaf(s1, bf16lo(u1), acc0); acc1 = fmaf(s1, bf16hi(u1), acc1);
                acc0 = fmaf(s2, bf16lo(u2), acc0); acc1 = fmaf(s2, bf16hi(u2), acc1);
                acc0 = fmaf(s3, bf16lo(u3), acc0); acc1 = fmaf(s3, bf16hi(u3), acc1);
                acc0 = fmaf(s4, bf16lo(u4), acc0); acc1 = fmaf(s4, bf16hi(u4), acc1);
                acc0 = fmaf(s5, bf16lo(u5), acc0); acc1 = fmaf(s5, bf16hi(u5), acc1);
                acc0 = fmaf(s6, bf16lo(u6), acc0); acc1 = fmaf(s6, bf16hi(u6), acc1);
                acc0 = fmaf(s7, bf16lo(u7), acc0); acc1 = fmaf(s7, bf16hi(u7), acc1);
            }
            for (; j + 4 <= mt; j += 4) {
                int   o0 = __shfl(ofs, j + 0), o1 = __shfl(ofs, j + 1);
                int   o2 = __shfl(ofs, j + 2), o3 = __shfl(ofs, j + 3);
                float s0 = __shfl(sc, j + 0), s1 = __shfl(sc, j + 1);
                float s2 = __shfl(sc, j + 2), s3 = __shfl(sc, j + 3);
                uint32_t u0 = hf[(size_t)(o0 + lane)];
                uint32_t u1 = hf[(size_t)(o1 + lane)];
                uint32_t u2 = hf[(size_t)(o2 + lane)];
                uint32_t u3 = hf[(size_t)(o3 + lane)];
                acc0 = fmaf(s0, bf16lo(u0), acc0); acc1 = fmaf(s0, bf16hi(u0), acc1);
                acc0 = fmaf(s1, bf16lo(u1), acc0); acc1 = fmaf(s1, bf16hi(u1), acc1);
                acc0 = fmaf(s2, bf16lo(u2), acc0); acc1 = fmaf(s2, bf16hi(u2), acc1);
                acc0 = fmaf(s3, bf16lo(u3), acc0); acc1 = fmaf(s3, bf16hi(u3), acc1);
            }
            for (; j < mt; ++j) {
                int oj = __shfl(ofs, j); float sj = __shfl(sc, j);
                uint32_t uj = hf[(size_t)(oj + lane)];
                acc0 = fmaf(sj, bf16lo(uj), acc0); acc1 = fmaf(sj, bf16hi(uj), acc1);
            }
        } else {
            // ultra-rare exact fallback (cf+cb > 64)
            for (int j = 0; j < cf; ++j) {
                int nb = adj_f[node * CAP + j];
                float dj = dvsf * dinv_f[nb];
                uint32_t u = hf[(size_t)nb * 64 + lane];
                acc0 = fmaf(dj, bf16lo(u), acc0); acc1 = fmaf(dj, bf16hi(u), acc1);
            }
            for (int j = 0; j < cb; ++j) {
                int nb = adj_b[node * CAP + j];
                float dj = dvsb * dinv_b[nb];
                uint32_t u = hf[(size_t)(nwords + nb * 64 + lane)];
                acc0 = fmaf(dj, bf16lo(u), acc0); acc1 = fmaf(dj, bf16hi(u), acc1);
            }
        }

        const float2 biasf = ((const float2*)bf)[lane];
        const float2 biasb = ((const float2*)bb)[lane];
        float v0 = acc0 + biasf.x + biasb.x;
        float v1 = acc1 + biasf.y + biasb.y;
        ((float2*)out)[(size_t)node * 64 + lane] =
            make_float2(fmaxf(v0, 0.0f), fmaxf(v1, 0.0f));
        return;
    }

    // ---- fixup blocks: exact recompute of overflowed rows ----
    int nov = *ovcnt; if (nov > OVMAX) nov = OVMAX;
    if (nov == 0) return;
    __shared__ int lst[4096];
    __shared__ int lcnt;
    const int tid = threadIdx.x;
    for (int i = bid - gnode; i < nov; i += 8) {
        int code = ovlist[i];
        int e = code >> 1, dir = code & 1;
        int node = dir ? src[e] : dst[e];
        float acc0 = 0.f, acc1 = 0.f;
        for (int d2 = 0; d2 < 2; ++d2) {
            const int* key = d2 ? src : dst;
            const int* val = d2 ? dst : src;
            const float* dinv = d2 ? dinv_b : dinv_f;
            int base = d2 ? nwords : 0;
            float dvs = dinv[node];
            float s0 = 0.f, s1 = 0.f;
            if (tid < 64) {
                uint32_t u = hf[(size_t)(base + node * 64 + tid)];
                s0 = dvs * bf16lo(u); s1 = dvs * bf16hi(u);
            }
            for (int start = 0; start < ne; start += 4096) {
                if (tid == 0) lcnt = 0;
                __syncthreads();
                int end = min(start + 4096, ne);
                for (int e2 = start + tid; e2 < end; e2 += BLK)
                    if (key[e2] == node) { int q = atomicAdd(&lcnt, 1); lst[q] = val[e2]; }
                __syncthreads();
                int mm = lcnt;
                if (tid < 64) {
                    for (int j = 0; j < mm; ++j) {
                        int nb = lst[j];
                        float dv = dinv[nb];
                        uint32_t u = hf[(size_t)(base + nb * 64 + tid)];
                        s0 = fmaf(dv, bf16lo(u), s0);
                        s1 = fmaf(dv, bf16hi(u), s1);
                    }
                }
                __syncthreads();
            }
            if (tid < 64) { acc0 += dvs * s0; acc1 += dvs * s1; }
        }
        if (tid < 64) {
            float2 biasf = ((const float2*)bf)[tid];
            float2 biasb = ((const float2*)bb)[tid];
            float v0 = acc0 + biasf.x + biasb.x;
            float v1 = acc1 + biasf.y + biasb.y;
            ((float2*)out)[(size_t)node * 64 + tid] =
                make_float2(fmaxf(v0, 0.0f), fmaxf(v1, 0.0f));
        }
        __syncthreads();
    }
}

// ============================================================ launcher =====
extern "C" void kernel_launch(void* const* d_in, const int* in_sizes, int n_in,
                              void* d_out, int out_size, void* d_ws, size_t ws_size,
                              hipStream_t stream) {
    const float* x  = (const float*)d_in[0];
    const int*   ei = (const int*)d_in[1];
    const float* Wf = (const float*)d_in[2];
    const float* bf = (const float*)d_in[3];
    const float* Wb = (const float*)d_in[4];
    const float* bb = (const float*)d_in[5];

    const int n  = in_sizes[0] / 128;   // 50000
    const int ne = in_sizes[1] / 2;     // 625000
    const int* src = ei;
    const int* dst = ei + ne;
    float* out = (float*)d_out;

    // workspace layout (16B-aligned; n, ne multiples of 4)
    // h_f and h_b contiguous (gather addresses h_b as h_f + nwords dwords)
    char* w = (char*)d_ws;
    unsigned short* h_f = (unsigned short*)w;   w += (size_t)n * 128 * 2;
    unsigned short* h_b = (unsigned short*)w;   w += (size_t)n * 128 * 2;
    unsigned short* adj_f = (unsigned short*)w; w += (size_t)n * CAP * 2;  // 4 MB
    unsigned short* adj_b = (unsigned short*)w; w += (size_t)n * CAP * 2;
    unsigned char* rank_f = (unsigned char*)w;  w += (size_t)ne;           // 0.6 MB
    unsigned char* rank_b = (unsigned char*)w;  w += (size_t)ne;
    float* dinv_f = (float*)w;                  w += (size_t)n * 4;
    float* dinv_b = (float*)w;                  w += (size_t)n * 4;
    unsigned short* WTf = (unsigned short*)w;   w += 128 * 128 * 2;
    unsigned short* WTb = (unsigned short*)w;   w += 128 * 128 * 2;
    int* cnt_f = (int*)w;                       w += (size_t)n * 4;   // ---- zero
    int* cnt_b = (int*)w;                       w += (size_t)n * 4;   //  region
    int* ovcnt = (int*)w;                       w += 8 * 4;           // ----
    int* ovlist = (int*)w;                      w += OVMAX * 4;

    const int gc2   = (ne + BLK * 2 - 1) / (BLK * 2);   // 1221 count blocks
    const int gc    = (ne + BLK - 1) / BLK;             // 2442 fill blocks
    const int gg    = (n + 15) / 16;                    // 3125 gemm blocks
    const int gn    = (n + BLK - 1) / BLK;              // 196
    const int gnode = (n + 3) / 4;                      // 12500

    hipMemsetAsync(cnt_f, 0, (size_t)(2 * n + 8) * 4, stream);

    k_count <<<gc2 + 8, BLK, 0, stream>>>(src, dst, cnt_f, cnt_b,
                                          rank_f, rank_b, ne,
                                          Wf, Wb, WTf, WTb, gc2);

    k_phaseB<<<gc + gg + gn, BLK, 0, stream>>>(src, dst, rank_f, rank_b,
                                               adj_f, adj_b, ovcnt, ovlist, ne,
                                               x, WTf, WTb, h_f, h_b,
                                               cnt_f, cnt_b, dinv_f, dinv_b,
                                               n, gc, gg);

    k_gatherX<<<gnode + 8, BLK, 0, stream>>>(cnt_f, adj_f, cnt_b, adj_b,
                                             dinv_f, dinv_b,
                                             (const uint32_t*)h_f,
                                             (const uint32_t*)h_b,
                                             bf, bb, out, n, gnode, n * 64,
                                             ovcnt, ovlist, src, dst, ne);
}